// Round 3
// baseline (302.667 us; speedup 1.0000x reference)
//
#include <hip/hip_runtime.h>
#include <math.h>

typedef unsigned short u16;
typedef __attribute__((ext_vector_type(8))) short bf16x8;
typedef __attribute__((ext_vector_type(4))) float f32x4;

// ---- workspace layout (u16 elements) ----
constexpr int OFF_W1  = 0;        // [3][128][128] (l,h,c)  K-major in c
constexpr int OFF_W2  = 49152;    // [3][128][128] (l,c,h)  K-major in h
constexpr int OFF_GW  = 98304;    // [256][128]    (o,h)    K-major in h
constexpr int OFF_TGE = 131072;   // [4][48][64]  TGexp_n[a][row']  zeros on pads
constexpr int OFF_FGE = 143360;   // [4][64][64]  FGexp_n[row'][a]  zeros on pads
// total 159744 u16 = 319488 bytes of d_ws

// ---- LDS pool offsets (bytes) ----
constexpr int P_A1  = 0;        // [64][136] u16 : packed acts, later h2[row'][h]
constexpr int P_H1T = 17408;    // [128][72] u16 : h1T[h][row']
constexpr int P_G   = 35840;    // [48][136] u16 : G[a][h] per node
constexpr int P_G2T = 48896;    // [128][72] u16 : g2T[o][a-pad64] per node
constexpr int P_OUT = 17408;    // [64][132] f32 : out_s[row'][c]  (overlaps dead H1T/G)
constexpr int P_SZ  = 67328;

__device__ __forceinline__ u16 f2bf(float f) {
    unsigned u = __float_as_uint(f);
    u += 0x7FFFu + ((u >> 16) & 1u);   // RNE
    return (u16)(u >> 16);
}
__device__ __forceinline__ void st4bf(void* p, f32x4 v) {
    union { unsigned long long u; unsigned int w[2]; } d;
    d.w[0] = (unsigned)f2bf(v[0]) | ((unsigned)f2bf(v[1]) << 16);
    d.w[1] = (unsigned)f2bf(v[2]) | ((unsigned)f2bf(v[3]) << 16);
    *(unsigned long long*)p = d.u;
}
// batched-row map: row' -> (node, m);  l0: 0..3, l1: 16..27, l2: 32..51
__device__ __forceinline__ bool rowmap(int rp, int& n, int& m) {
    if (rp < 4)              { n = rp; m = 0; return true; }
    if (rp >= 16 && rp < 28) { int t = rp - 16; n = t / 3; m = 1 + t % 3; return true; }
    if (rp >= 32 && rp < 52) { int t = rp - 32; n = t / 5; m = 4 + t % 5; return true; }
    return false;
}

__global__ void prep_kernel(const float* __restrict__ w1, const float* __restrict__ gw,
                            const float* __restrict__ w2, const float* __restrict__ tg,
                            const float* __restrict__ fg, u16* __restrict__ wsb) {
    const int idx = blockIdx.x * blockDim.x + threadIdx.x;
    const int str = gridDim.x * blockDim.x;
    for (int i = idx; i < 49152; i += str) wsb[OFF_W1 + i] = f2bf(w1[i]);
    for (int i = idx; i < 49152; i += str) wsb[OFF_W2 + i] = f2bf(w2[i]);
    for (int i = idx; i < 32768; i += str) wsb[OFF_GW + i] = f2bf(gw[i]);
    for (int i = idx; i < 12288; i += str) {          // TGE: [n][a][row']
        int n = i / 3072, rem = i - n * 3072, a = rem >> 6, rp = rem & 63;
        int nn, m; float v = 0.f;
        if (a < 42 && rowmap(rp, nn, m) && nn == n) v = tg[a * 9 + m];
        wsb[OFF_TGE + i] = f2bf(v);
    }
    for (int i = idx; i < 16384; i += str) {          // FGE: [n][row'][a]
        int n = i >> 12, rem = i & 4095, rp = rem >> 6, a = rem & 63;
        int nn, m; float v = 0.f;
        if (a < 42 && rowmap(rp, nn, m) && nn == n) v = fg[m * 42 + a];
        wsb[OFF_FGE + i] = f2bf(v);
    }
}

#define MFMA16(A, B, C) __builtin_amdgcn_mfma_f32_16x16x32_bf16(A, B, C, 0, 0, 0)

__global__ __launch_bounds__(256, 2) void eqffn2(
    const float* __restrict__ x, const float* __restrict__ nwf,
    const float* __restrict__ b1f, const float* __restrict__ gbf,
    const float* __restrict__ b2f, const u16* __restrict__ wsb,
    float* __restrict__ out, int N)
{
    __shared__ __align__(16) unsigned char pool[P_SZ];
    __shared__ float sh_nw[384];
    __shared__ float sh_b1[128];
    __shared__ float sh_b2[128];
    __shared__ float sh_gb[256];

    u16*   A1  = (u16*)(pool + P_A1);     // [64][136]
    u16*   H1T = (u16*)(pool + P_H1T);    // [128][72]
    u16*   Gm  = (u16*)(pool + P_G);      // [48][136]
    u16*   G2T = (u16*)(pool + P_G2T);    // [128][72]
    float* OUTS = (float*)(pool + P_OUT); // [64][132]

    const int tid  = threadIdx.x;
    const int w    = tid >> 6;
    const int lane = tid & 63;
    const int q    = lane >> 4;
    const int r    = lane & 15;
    const int n0   = blockIdx.x * 4;

    // ---- init: zero A1 (pad rows must be 0) + g2T k-pad cols 48..63; stage smalls ----
    {
        unsigned long long* z = (unsigned long long*)A1;
        for (int i = tid; i < 2176; i += 256) z[i] = 0ull;
        for (int i = tid; i < 512; i += 256) {
            int h = i >> 2, p = i & 3;
            *(unsigned long long*)(pool + P_G2T + h * 144 + 96 + p * 8) = 0ull;
        }
    }
    for (int i = tid; i < 384; i += 256) sh_nw[i] = nwf[i];
    if (tid < 128) { sh_b1[tid] = b1f[tid]; sh_b2[tid] = b2f[tid]; }
    sh_gb[tid] = gbf[tid];
    __syncthreads();

    // ---- phase A: wave w <-> node n0+w; load x, RMS, pack+normalize -> A1 bf16 ----
    const int myn = n0 + w;
    float4 xv[5];
    float ss = 0.f;
    if (myn < N) {
        const float4* xr = (const float4*)(x + (size_t)myn * 1152);
        for (int i = lane, c2 = 0; i < 288; i += 64, ++c2) {
            float4 v = xr[i]; xv[c2] = v;
            ss += v.x * v.x + v.y * v.y + v.z * v.z + v.w * v.w;
        }
    }
    #pragma unroll
    for (int off = 32; off; off >>= 1) ss += __shfl_xor(ss, off);
    const float inv = 1.0f / sqrtf(ss * (1.0f / 1152.0f) + 1e-6f);
    if (myn < N) {
        for (int i = lane, c2 = 0; i < 288; i += 64, ++c2) {
            float4 v = xv[c2];
            #pragma unroll
            for (int e = 0; e < 4; ++e) {
                const int f = i * 4 + e;
                const float val = ((const float*)&v)[e] * inv;
                int row, c, l;
                if (f < 128)      { l = 0; c = f;            row = w; }
                else if (f < 512) { int t = f - 128; l = 1; c = t / 3; row = 16 + w * 3 + (t - c * 3); }
                else              { int t = f - 512; l = 2; c = t / 5; row = 32 + w * 5 + (t - c * 5); }
                A1[row * 136 + c] = f2bf(val * sh_nw[l * 128 + c]);
            }
        }
    }
    __syncthreads();

    // ---- GEMM1: C[row'64][h128] K=c128; cheap-write -> h1T[h][row'] ----
    {
        f32x4 acc[4][2];
        #pragma unroll
        for (int a = 0; a < 4; ++a)
            #pragma unroll
            for (int b = 0; b < 2; ++b)
                #pragma unroll
                for (int e = 0; e < 4; ++e) acc[a][b][e] = 0.f;
        #pragma unroll
        for (int mt = 0; mt < 4; ++mt) {
            const int l = (mt == 0) ? 0 : ((mt == 1) ? 1 : 2);
            #pragma unroll
            for (int kk = 0; kk < 4; ++kk) {
                bf16x8 af = *(const bf16x8*)&A1[(mt * 16 + r) * 136 + kk * 32 + q * 8];
                #pragma unroll
                for (int nt = 0; nt < 2; ++nt) {
                    const int h = (2 * w + nt) * 16 + r;
                    bf16x8 bf = *(const bf16x8*)&wsb[OFF_W1 + (l * 128 + h) * 128 + kk * 32 + q * 8];
                    acc[mt][nt] = MFMA16(af, bf, acc[mt][nt]);
                }
            }
        }
        #pragma unroll
        for (int nt = 0; nt < 2; ++nt) {
            const int h = (2 * w + nt) * 16 + r;
            const float bias = sh_b1[h];
            #pragma unroll
            for (int mt = 0; mt < 4; ++mt) {
                f32x4 v = acc[mt][nt];
                if (mt == 0) {
                    #pragma unroll
                    for (int e = 0; e < 4; ++e) v[e] += bias;   // pad rows killed by TGE zeros
                }
                st4bf(&H1T[h * 72 + mt * 16 + q * 4], v);
            }
        }
    }
    __syncthreads();

    // hoisted swiglu bias scalars
    float gbL[2], gbH[2];
    #pragma unroll
    for (int p = 0; p < 2; ++p) {
        const int oL = (2 * w + p) * 16 + r;
        gbL[p] = sh_gb[oL]; gbH[p] = sh_gb[128 + oL];
    }

    // from_grid accumulators, carried across the node loop
    f32x4 afg[2][4];
    #pragma unroll
    for (int a = 0; a < 2; ++a)
        #pragma unroll
        for (int b = 0; b < 4; ++b)
            #pragma unroll
            for (int e = 0; e < 4; ++e) afg[a][b][e] = 0.f;

    // ---- per-node grid pipeline ----
    for (int n = 0; n < 4; ++n) {
        // to_grid: C=G^T: M=h128, N=a48, K=row'64; A=h1T, B=TGE_n; write G[a][h]
        {
            const u16* TGn = wsb + OFF_TGE + n * 3072;
            f32x4 ac[2][3];
            #pragma unroll
            for (int a = 0; a < 2; ++a)
                #pragma unroll
                for (int b = 0; b < 3; ++b)
                    #pragma unroll
                    for (int e = 0; e < 4; ++e) ac[a][b][e] = 0.f;
            #pragma unroll
            for (int kk = 0; kk < 2; ++kk) {
                bf16x8 af[2];
                #pragma unroll
                for (int Mt = 0; Mt < 2; ++Mt)
                    af[Mt] = *(const bf16x8*)&H1T[((2 * w + Mt) * 16 + r) * 72 + kk * 32 + q * 8];
                #pragma unroll
                for (int nt = 0; nt < 3; ++nt) {
                    bf16x8 bf = *(const bf16x8*)&TGn[(nt * 16 + r) * 64 + kk * 32 + q * 8];
                    #pragma unroll
                    for (int Mt = 0; Mt < 2; ++Mt) ac[Mt][nt] = MFMA16(af[Mt], bf, ac[Mt][nt]);
                }
            }
            #pragma unroll
            for (int nt = 0; nt < 3; ++nt)
                #pragma unroll
                for (int Mt = 0; Mt < 2; ++Mt)
                    st4bf(&Gm[(nt * 16 + r) * 136 + (2 * w + Mt) * 16 + q * 4], ac[Mt][nt]);
        }
        __syncthreads();

        // swiglu: C=z[a48][o256] K=h128; A=G, B=gw; silu-pair epilogue -> g2T[o][a]
        {
            f32x4 aL[2][3], aH[2][3];
            #pragma unroll
            for (int p = 0; p < 2; ++p)
                #pragma unroll
                for (int Mt = 0; Mt < 3; ++Mt)
                    #pragma unroll
                    for (int e = 0; e < 4; ++e) { aL[p][Mt][e] = 0.f; aH[p][Mt][e] = 0.f; }
            #pragma unroll
            for (int kk = 0; kk < 4; ++kk) {
                bf16x8 ga[3];
                #pragma unroll
                for (int Mt = 0; Mt < 3; ++Mt)
                    ga[Mt] = *(const bf16x8*)&Gm[(Mt * 16 + r) * 136 + kk * 32 + q * 8];
                #pragma unroll
                for (int p = 0; p < 2; ++p) {
                    const int oL = (2 * w + p) * 16 + r;
                    bf16x8 bL = *(const bf16x8*)&wsb[OFF_GW + oL * 128 + kk * 32 + q * 8];
                    bf16x8 bH = *(const bf16x8*)&wsb[OFF_GW + (oL + 128) * 128 + kk * 32 + q * 8];
                    #pragma unroll
                    for (int Mt = 0; Mt < 3; ++Mt) {
                        aL[p][Mt] = MFMA16(ga[Mt], bL, aL[p][Mt]);
                        aH[p][Mt] = MFMA16(ga[Mt], bH, aH[p][Mt]);
                    }
                }
            }
            #pragma unroll
            for (int p = 0; p < 2; ++p) {
                const int oL = (2 * w + p) * 16 + r;
                #pragma unroll
                for (int Mt = 0; Mt < 3; ++Mt) {
                    f32x4 g;
                    #pragma unroll
                    for (int e = 0; e < 4; ++e) {
                        const float zl = aL[p][Mt][e] + gbL[p];
                        const float zh = aH[p][Mt][e] + gbH[p];
                        g[e] = zl * (1.0f / (1.0f + __expf(-zl))) * zh;  // FGE zeros kill a>=42
                    }
                    st4bf(&G2T[oL * 72 + Mt * 16 + q * 4], g);
                }
            }
        }
        __syncthreads();

        // from_grid: C=h2^T: M=h128, N=row'64, K=a64; A=g2T, B=FGE_n; accumulate in regs
        {
            const u16* FGn = wsb + OFF_FGE + n * 4096;
            #pragma unroll
            for (int kk = 0; kk < 2; ++kk) {
                bf16x8 af[2];
                #pragma unroll
                for (int Mt = 0; Mt < 2; ++Mt)
                    af[Mt] = *(const bf16x8*)&G2T[((2 * w + Mt) * 16 + r) * 72 + kk * 32 + q * 8];
                #pragma unroll
                for (int nt = 0; nt < 4; ++nt) {
                    bf16x8 bf = *(const bf16x8*)&FGn[(nt * 16 + r) * 64 + kk * 32 + q * 8];
                    #pragma unroll
                    for (int Mt = 0; Mt < 2; ++Mt) afg[Mt][nt] = MFMA16(af[Mt], bf, afg[Mt][nt]);
                }
            }
        }
        // no barrier: next to_grid's barrier orders g2T reuse
    }

    // ---- write h2[row'][h] into A1 region ----
    #pragma unroll
    for (int nt = 0; nt < 4; ++nt)
        #pragma unroll
        for (int Mt = 0; Mt < 2; ++Mt)
            st4bf(&A1[(nt * 16 + r) * 136 + (2 * w + Mt) * 16 + q * 4], afg[Mt][nt]);
    __syncthreads();

    // ---- GEMM2: C=out^T[c128][row'64] K=h128; A=w2[l(nt)], B=h2; write out_s f32 ----
    {
        f32x4 ac[2][4];
        #pragma unroll
        for (int a = 0; a < 2; ++a)
            #pragma unroll
            for (int b = 0; b < 4; ++b)
                #pragma unroll
                for (int e = 0; e < 4; ++e) ac[a][b][e] = 0.f;
        #pragma unroll
        for (int kk = 0; kk < 4; ++kk) {
            bf16x8 bh[4];
            #pragma unroll
            for (int nt = 0; nt < 4; ++nt)
                bh[nt] = *(const bf16x8*)&A1[(nt * 16 + r) * 136 + kk * 32 + q * 8];
            #pragma unroll
            for (int Mt = 0; Mt < 2; ++Mt) {
                const int c = (2 * w + Mt) * 16 + r;
                bf16x8 a0 = *(const bf16x8*)&wsb[OFF_W2 + (0 * 128 + c) * 128 + kk * 32 + q * 8];
                bf16x8 a1 = *(const bf16x8*)&wsb[OFF_W2 + (1 * 128 + c) * 128 + kk * 32 + q * 8];
                bf16x8 a2 = *(const bf16x8*)&wsb[OFF_W2 + (2 * 128 + c) * 128 + kk * 32 + q * 8];
                ac[Mt][0] = MFMA16(a0, bh[0], ac[Mt][0]);
                ac[Mt][1] = MFMA16(a1, bh[1], ac[Mt][1]);
                ac[Mt][2] = MFMA16(a2, bh[2], ac[Mt][2]);
                ac[Mt][3] = MFMA16(a2, bh[3], ac[Mt][3]);
            }
        }
        #pragma unroll
        for (int Mt = 0; Mt < 2; ++Mt) {
            const int cb = (2 * w + Mt) * 16 + q * 4;
            const float4 bias = *(const float4*)&sh_b2[cb];
            #pragma unroll
            for (int nt = 0; nt < 4; ++nt) {
                const int rp = nt * 16 + r;
                f32x4 v = ac[Mt][nt];
                if (nt == 0 && r < 4) {
                    v[0] += bias.x; v[1] += bias.y; v[2] += bias.z; v[3] += bias.w;
                }
                *(float4*)&OUTS[rp * 132 + cb] = *(float4*)&v;
            }
        }
    }
    __syncthreads();

    // ---- unpack: coalesced float4 stores to global ----
    {
        const int nloc = tid >> 6;
        const int gn = n0 + nloc;
        if (gn < N) {
            float4* orow = (float4*)(out + (size_t)gn * 1152);
            for (int j = lane; j < 288; j += 64) {
                float4 v;
                if (j < 32) {
                    v = *(const float4*)&OUTS[nloc * 132 + j * 4];
                } else if (j < 128) {
                    const int t = j * 4 - 128;
                    #pragma unroll
                    for (int e = 0; e < 4; ++e) {
                        const int te = t + e, c = te / 3, mm = te - 3 * c;
                        ((float*)&v)[e] = OUTS[(16 + nloc * 3 + mm) * 132 + c];
                    }
                } else {
                    const int t = j * 4 - 512;
                    #pragma unroll
                    for (int e = 0; e < 4; ++e) {
                        const int te = t + e, c = te / 5, mm = te - 5 * c;
                        ((float*)&v)[e] = OUTS[(32 + nloc * 5 + mm) * 132 + c];
                    }
                }
                orow[j] = v;
            }
        }
    }
}

extern "C" void kernel_launch(void* const* d_in, const int* in_sizes, int n_in,
                              void* d_out, int out_size, void* d_ws, size_t ws_size,
                              hipStream_t stream)
{
    const float* x  = (const float*)d_in[0];
    const float* nw = (const float*)d_in[1];
    const float* w1 = (const float*)d_in[2];
    const float* b1 = (const float*)d_in[3];
    const float* gw = (const float*)d_in[4];
    const float* gb = (const float*)d_in[5];
    const float* w2 = (const float*)d_in[6];
    const float* b2 = (const float*)d_in[7];
    const float* tg = (const float*)d_in[8];
    const float* fg = (const float*)d_in[9];
    float* out = (float*)d_out;
    u16* wsb = (u16*)d_ws;

    const int N = in_sizes[0] / 1152;
    prep_kernel<<<128, 256, 0, stream>>>(w1, gw, w2, tg, fg, wsb);
    eqffn2<<<(N + 3) / 4, 256, 0, stream>>>(x, nw, b1, gb, b2, wsb, out, N);
}